// Round 9
// baseline (35769.815 us; speedup 1.0000x reference)
//
#include <hip/hip_runtime.h>

// Problem dims
#define Bn   64
#define Sn   512
#define Dn   768
#define Hn   384
#define G4n  1536   // 4*H
#define Tn   9
#define SCHn 64     // S-chunk
#define NCH  8      // Sn / SCHn

// ---- workspace layout (in floats) ----
#define OFF_WIHT  0ull
#define SZ_WIHT   (4ull * Dn * G4n)                       // 4,718,592
#define OFF_GATES (OFF_WIHT + SZ_WIHT)
#define SZ_GCH    (2ull * Bn * SCHn * G4n)                // per-layer chunk slice
#define SZ_GATES  (2ull * SZ_GCH)                         // 25,165,824
#define OFF_H1    (OFF_GATES + SZ_GATES)
#define SZ_H1     ((unsigned long long)Bn * Sn * Dn)      // 25,165,824
#define OFF_EMP   (OFF_H1 + SZ_H1)
#define SZ_EMP    (2ull * Bn * Sn * Tn)
#define OFF_EM    (OFF_EMP + SZ_EMP)
#define SZ_EM     ((unsigned long long)Bn * Sn * Tn)
#define OFF_HBUF  (OFF_EM + SZ_EM)
#define SZ_HBUF   (8ull * Bn * Hn)                        // [L][parity][dir][b][d]
#define OFF_CST   (OFF_HBUF + SZ_HBUF)
#define SZ_CST    (4ull * Bn * Hn)                        // [L][dir][b][d]
#define OFF_LP    (OFF_CST + SZ_CST)
#define SZ_LP     64ull
#define OFF_STAMP (OFF_LP + SZ_LP)
// stamps: [L:2][dir:2][bg:8][dg:32] lines of 32 ints; dwords 0/1 = wave0/1 stamps
#define STAMP_TOTAL (2 * 2 * 8 * 32 * 32)

static __device__ __forceinline__ float sigf(float x) { return 1.f / (1.f + expf(-x)); }

// ---- LLC primitives: relaxed system scope (bypass L1/L2, no cache maintenance) ----
static __device__ __forceinline__ unsigned long long llc_load_u64(const unsigned long long* p) {
    return __hip_atomic_load(p, __ATOMIC_RELAXED, __HIP_MEMORY_SCOPE_SYSTEM);
}
static __device__ __forceinline__ void llc_store_f32(float* p, float v) {
    __hip_atomic_store(p, v, __ATOMIC_RELAXED, __HIP_MEMORY_SCOPE_SYSTEM);
}

// ---------------- weight transpose: [ld][N=1536][K] -> [ld][K][N] ----------------
__global__ void transpose_w(const float* __restrict__ in, float* __restrict__ out,
                            int K, int total)
{
    const int nk = G4n * K;
    for (int idx = blockIdx.x * blockDim.x + threadIdx.x; idx < total;
         idx += gridDim.x * blockDim.x) {
        const int ld = idx / nk;
        const int r  = idx - ld * nk;
        const int k  = r / G4n;
        const int n  = r - k * G4n;
        out[idx] = in[(size_t)ld * nk + (size_t)n * K + k];
    }
}

// ---------------- stamp init ----------------
__global__ void init_bar(int* __restrict__ st)
{
    for (int i = blockIdx.x * 256 + threadIdx.x; i < STAMP_TOTAL; i += 64 * 256)
        st[i] = 0;
}

// ---------------- gates GEMM: G[m][col'] = A_row(m) . WihT[:,n] + bias[n] ----------------
// col' = (n%384)*4 + n/384 ; m = (dir*64 + b)*SCHn + j
__global__ __launch_bounds__(256) void gemm_gates(
    const float* __restrict__ A,      // [64][512][768] (bert or h1)
    const float* __restrict__ WihT,   // [2][2][768][1536]
    const float* __restrict__ bvec,   // [2][2][1536]
    float* __restrict__ G,            // per-layer slice [2][64][SCHn][1536]
    int layer, int chunk)
{
    const int tid = threadIdx.x;
    const int nb  = blockIdx.x;       // 0..11
    const int mb  = blockIdx.y;       // 0..63
    const int m0  = mb * 128;
    const int dir = mb >> 5;          // 32 tiles per dir
    const int n0c = nb * 128;

    __shared__ __align__(16) float As[8][128];
    __shared__ __align__(16) float Bs[8][128];

    const float* BT   = WihT + (size_t)(layer * 2 + dir) * Dn * G4n;
    const float* bias = bvec + (size_t)(layer * 2 + dir) * G4n;

    const int lrow = tid >> 1;            // 0..127
    const int kq   = (tid & 1) * 4;
    const int grow = m0 + lrow;
    const int rem  = grow & (Bn * SCHn - 1);   // & 4095
    const int bb   = rem >> 6;                 // / SCHn
    const int j    = rem & (SCHn - 1);
    const int p    = chunk * SCHn + j;
    const int s    = dir ? (Sn - 1 - p) : p;
    const float* arow = A + ((size_t)bb * Sn + s) * Dn;

    const int kr = tid >> 5;              // 0..7
    const int nq = (tid & 31) * 4;

    const int tx = tid & 15, ty = tid >> 4;

    float acc[8][8];
    #pragma unroll
    for (int i = 0; i < 8; ++i)
        #pragma unroll
        for (int q = 0; q < 8; ++q) acc[i][q] = 0.f;

    for (int k0 = 0; k0 < Dn; k0 += 8) {
        const float4 av = *(const float4*)(arow + k0 + kq);
        const float4 bv = *(const float4*)(BT + (size_t)(k0 + kr) * G4n + n0c + nq);
        __syncthreads();
        As[kq + 0][lrow] = av.x;
        As[kq + 1][lrow] = av.y;
        As[kq + 2][lrow] = av.z;
        As[kq + 3][lrow] = av.w;
        *(float4*)&Bs[kr][nq] = bv;
        __syncthreads();
        #pragma unroll
        for (int kk = 0; kk < 8; ++kk) {
            float a8[8], b8[8];
            #pragma unroll
            for (int i = 0; i < 8; ++i) a8[i] = As[kk][ty * 8 + i];
            #pragma unroll
            for (int i = 0; i < 8; ++i) b8[i] = Bs[kk][tx * 8 + i];
            #pragma unroll
            for (int i = 0; i < 8; ++i)
                #pragma unroll
                for (int q = 0; q < 8; ++q) acc[i][q] += a8[i] * b8[q];
        }
    }

    float bias8[8];
    #pragma unroll
    for (int q = 0; q < 8; ++q) bias8[q] = bias[n0c + tx * 8 + q];

    #pragma unroll
    for (int i = 0; i < 8; ++i) {
        const int row = m0 + ty * 8 + i;
        float* gr = G + (size_t)row * G4n;
        #pragma unroll
        for (int q = 0; q < 8; ++q) {
            const int n = n0c + tx * 8 + q;
            const int g = n / 384;
            const int d2 = n - g * 384;
            gr[d2 * 4 + g] = acc[i][q] + bias8[q];
        }
    }
}

// ---------------- persistent LSTM recurrence; dual-task capable ----------------
// grid 512 (single task) or 1024 (two independent (layer,chunk) tasks).
// Per half: (dir:2)x(bg:8 of 8 batches)x(dg:32 of 12 dims).
// Sync: per-wave stamp dwords in one line; raw s_barrier (lgkm-only drain).
__global__ __launch_bounds__(256, 4) void lstm_persist(
    const float* __restrict__ gates,  // [L][2][64][SCHn][1536] col-interleaved
    const float* __restrict__ Whh,    // [2][2][1536][384]
    const float* __restrict__ fcw,    // [9][768]
    float* __restrict__ h1,           // [64][512][768]  (layer 0 only)
    float* __restrict__ emP,          // [2][64][512][9] (layer 1 only)
    float* __restrict__ hbuf,         // [L][parity][dir][64][384]
    float* __restrict__ cst,          // [L][dir][64][384]
    int* __restrict__ stamps,
    int la, int ca, int lb, int cb)
{
    const int tid  = threadIdx.x;
    const int bid  = blockIdx.x;
    const int half = bid >> 9;
    const int layer = half ? lb : la;
    const int chunk = half ? cb : ca;
    const int lbid = bid & 511;
    const int dir  = lbid >> 8;
    const int bg   = (lbid >> 5) & 7;
    const int dg   = lbid & 31;
    const int b0 = bg * 8, d0 = dg * 12;

    __shared__ __align__(16) float hstage[8][396];
    __shared__ __align__(16) float red[4][16][28];
    __shared__ float cs[8][12];
    __shared__ float fcwl[Hn];

    const int ct = tid & 15;
    const int kq = tid >> 4;
    const int k0 = kq * 24;
    const int sbb = tid >> 5, skq = tid & 31;
    const bool pw = (tid < 96);
    const int pb = tid / 12, pdd = tid - pb * 12;
    const int lane = tid & 63, wv = tid >> 6;

    const float* gch = gates + (size_t)layer * SZ_GCH;
    int* sgrp = stamps + (((layer * 2 + dir) * 8 + bg) * 32) * 32;
    const unsigned long long* pollp = (const unsigned long long*)(sgrp + skq * 32);

    // ---- Whh slice into registers ----
    float wreg[72];
    {
        const float* Wbase = Whh + (size_t)(layer * 2 + dir) * G4n * Hn;
        #pragma unroll
        for (int c = 0; c < 3; ++c) {
            const int cc = ct * 3 + c;               // col' = dd*4+g
            const int dd = cc >> 2, g = cc & 3;
            const float* wr = Wbase + (size_t)(g * Hn + d0 + dd) * Hn + k0;
            #pragma unroll
            for (int kk = 0; kk < 24; kk += 4) {
                const float4 w4 = *(const float4*)(wr + kk);
                wreg[c * 24 + kk + 0] = w4.x;
                wreg[c * 24 + kk + 1] = w4.y;
                wreg[c * 24 + kk + 2] = w4.z;
                wreg[c * 24 + kk + 3] = w4.w;
            }
        }
    }

    const bool fcwg = (layer == 1) && (dg < Tn);
    if (fcwg) {
        for (int k2 = tid; k2 < Hn; k2 += 256)
            fcwl[k2] = fcw[dg * Dn + dir * Hn + k2];
    }

    if (pw) {
        cs[pb][pdd] = (chunk == 0) ? 0.f
            : cst[((size_t)(layer * 2 + dir) * Bn + b0 + pb) * Hn + d0 + pdd];
    }
    __syncthreads();

    // prologue gates prefetch (drained by first poll — once per dispatch)
    float4 g4 = make_float4(0.f, 0.f, 0.f, 0.f);
    if (pw)
        g4 = *(const float4*)(gch + ((size_t)(dir * Bn + b0 + pb) * SCHn + 0) * G4n
                              + (d0 + pdd) * 4);

    for (int j = 0; j < SCHn; ++j) {
        const int sg = chunk * SCHn + j;
        const int p_rd = sg & 1, p_wr = (sg + 1) & 1;
        const int s = dir ? (Sn - 1 - sg) : sg;

        // ---- poll producer stamps (both wave-dwords) + stage h ----
        if (chunk == 0 && j == 0) {
            #pragma unroll
            for (int i = 0; i < 6; ++i)
                *(float2*)&hstage[sbb][skq * 12 + 2 * i] = make_float2(0.f, 0.f);
        } else {
            const int need = sg;
            unsigned long long sv = llc_load_u64(pollp);
            while ((int)(sv & 0xffffffffu) < need || (int)(sv >> 32) < need) {
                __builtin_amdgcn_s_sleep(1);
                sv = llc_load_u64(pollp);
            }
            const unsigned long long* hsrc = (const unsigned long long*)
                (hbuf + (((size_t)layer * 2 + p_rd) * 2 + dir) * ((size_t)Bn * Hn)
                 + (size_t)(b0 + sbb) * Hn) + skq * 6;
            unsigned long long v[6];
            #pragma unroll
            for (int i = 0; i < 6; ++i) v[i] = llc_load_u64(hsrc + i);
            #pragma unroll
            for (int i = 0; i < 6; ++i) {
                float2 f2;
                f2.x = __uint_as_float((unsigned int)v[i]);
                f2.y = __uint_as_float((unsigned int)(v[i] >> 32));
                *(float2*)&hstage[sbb][skq * 12 + 2 * i] = f2;
            }
        }

        // next step's gates — issued AFTER poll, stays outstanding across raw barriers
        float4 g4n = make_float4(0.f, 0.f, 0.f, 0.f);
        if (pw && (j + 1) < SCHn)
            g4n = *(const float4*)(gch + ((size_t)(dir * Bn + b0 + pb) * SCHn + (j + 1)) * G4n
                                   + (d0 + pdd) * 4);

        // B: LDS-only drain + barrier (vmem stays in flight)
        asm volatile("s_waitcnt lgkmcnt(0)\n\ts_barrier" ::: "memory");

        // ---- recurrent matvec ----
        float acc[24];
        #pragma unroll
        for (int i = 0; i < 24; ++i) acc[i] = 0.f;
        #pragma unroll
        for (int b = 0; b < 8; ++b) {
            const float* hp = &hstage[b][k0];
            float hv[24];
            #pragma unroll
            for (int i = 0; i < 6; ++i) {
                const float4 h4 = *(const float4*)(hp + i * 4);
                hv[i * 4 + 0] = h4.x; hv[i * 4 + 1] = h4.y;
                hv[i * 4 + 2] = h4.z; hv[i * 4 + 3] = h4.w;
            }
            #pragma unroll
            for (int c = 0; c < 3; ++c)
                #pragma unroll
                for (int kk = 0; kk < 24; ++kk)
                    acc[b * 3 + c] += hv[kk] * wreg[c * 24 + kk];
        }
        #pragma unroll
        for (int i = 0; i < 24; ++i) {
            acc[i] += __shfl_xor(acc[i], 16);
            acc[i] += __shfl_xor(acc[i], 32);
        }
        if (lane < 16) {
            #pragma unroll
            for (int i = 0; i < 24; i += 4) {
                float4 t4; t4.x = acc[i]; t4.y = acc[i + 1];
                t4.z = acc[i + 2]; t4.w = acc[i + 3];
                *(float4*)&red[wv][lane][i] = t4;
            }
        }

        // fused FC for step sg-1 (hstage still holds h_{sg-1}↔? no: holds h_{sg}; FC uses it for step sg-1's OUTPUT h which IS h_{sg}) 
        if (fcwg && j >= 1) {
            const int sgp = sg - 1;
            const int sprev = dir ? (Sn - 1 - sgp) : sgp;
            const float* hp2 = &hstage[sbb][skq * 12];
            const float* wp2 = &fcwl[skq * 12];
            float e2 = 0.f;
            #pragma unroll
            for (int q = 0; q < 12; ++q) e2 += hp2[q] * wp2[q];
            e2 += __shfl_down(e2, 16, 32);
            e2 += __shfl_down(e2, 8, 32);
            e2 += __shfl_down(e2, 4, 32);
            e2 += __shfl_down(e2, 2, 32);
            e2 += __shfl_down(e2, 1, 32);
            if (skq == 0)
                emP[((size_t)(dir * Bn + b0 + sbb) * Sn + sprev) * Tn + dg] = e2;
        }

        // C
        asm volatile("s_waitcnt lgkmcnt(0)\n\ts_barrier" ::: "memory");

        // ---- final sum + pointwise ----
        if (pw) {
            float pre[4];
            #pragma unroll
            for (int g = 0; g < 4; ++g) {
                const int cc = pdd * 4 + g;
                const int ct2 = cc / 3;
                const int e = pb * 3 + (cc - ct2 * 3);
                pre[g] = red[0][ct2][e] + red[1][ct2][e]
                       + red[2][ct2][e] + red[3][ct2][e];
            }
            const float ii = sigf(pre[0] + g4.x);
            const float ff = sigf(pre[1] + g4.y);
            const float gg = tanhf(pre[2] + g4.z);
            const float oo = sigf(pre[3] + g4.w);
            const float cn = ff * cs[pb][pdd] + ii * gg;
            cs[pb][pdd] = cn;
            const float hn = oo * tanhf(cn);
            llc_store_f32(&hbuf[(((size_t)layer * 2 + p_wr) * 2 + dir) * ((size_t)Bn * Hn)
                                + (size_t)(b0 + pb) * Hn + d0 + pdd], hn);
            if (layer == 0)
                h1[((size_t)(b0 + pb) * Sn + s) * Dn + dir * Hn + d0 + pdd] = hn;
        }
        // per-wave arrive: drain own stores, stamp own dword (waves 0,1 only)
        if (tid < 128) {
            asm volatile("s_waitcnt vmcnt(0)" ::: "memory");
            if ((tid & 63) == 0)
                __hip_atomic_store(sgrp + dg * 32 + (tid >> 6), sg + 1,
                                   __ATOMIC_RELAXED, __HIP_MEMORY_SCOPE_SYSTEM);
        }
        g4 = g4n;
    }

    // ---- epilogue: FC for this chunk's last step (layer 1) ----
    if (fcwg) {
        const int sgl = chunk * SCHn + SCHn - 1;
        const int need = sgl + 1;
        unsigned long long sv = llc_load_u64(pollp);
        while ((int)(sv & 0xffffffffu) < need || (int)(sv >> 32) < need) {
            __builtin_amdgcn_s_sleep(1);
            sv = llc_load_u64(pollp);
        }
        const int pp = (sgl + 1) & 1;
        const unsigned long long* hsrc = (const unsigned long long*)
            (hbuf + (((size_t)layer * 2 + pp) * 2 + dir) * ((size_t)Bn * Hn)
             + (size_t)(b0 + sbb) * Hn) + skq * 6;
        unsigned long long v[6];
        #pragma unroll
        for (int i = 0; i < 6; ++i) v[i] = llc_load_u64(hsrc + i);
        #pragma unroll
        for (int i = 0; i < 6; ++i) {
            float2 f2;
            f2.x = __uint_as_float((unsigned int)v[i]);
            f2.y = __uint_as_float((unsigned int)(v[i] >> 32));
            *(float2*)&hstage[sbb][skq * 12 + 2 * i] = f2;
        }
        __syncthreads();
        const int sprev = dir ? (Sn - 1 - sgl) : sgl;
        const float* hp2 = &hstage[sbb][skq * 12];
        const float* wp2 = &fcwl[skq * 12];
        float e2 = 0.f;
        #pragma unroll
        for (int q = 0; q < 12; ++q) e2 += hp2[q] * wp2[q];
        e2 += __shfl_down(e2, 16, 32);
        e2 += __shfl_down(e2, 8, 32);
        e2 += __shfl_down(e2, 4, 32);
        e2 += __shfl_down(e2, 2, 32);
        e2 += __shfl_down(e2, 1, 32);
        if (skq == 0)
            emP[((size_t)(dir * Bn + b0 + sbb) * Sn + sprev) * Tn + dg] = e2;
    }

    if (pw)
        cst[((size_t)(layer * 2 + dir) * Bn + b0 + pb) * Hn + d0 + pdd] = cs[pb][pdd];
}

// ---------------- emission combine ----------------
__global__ void em_combine(const float* __restrict__ emP, const float* __restrict__ fcb,
                           float* __restrict__ em)
{
    const int idx = blockIdx.x * 256 + threadIdx.x;
    if (idx < Bn * Sn * Tn) {
        const int t = idx % Tn;
        em[idx] = emP[idx] + emP[(size_t)Bn * Sn * Tn + idx] + fcb[t];
    }
}

// ---------------- CRF negative log-likelihood ----------------
__global__ __launch_bounds__(64) void crf_loss(
    const float* __restrict__ em, const int* __restrict__ y,
    const float* __restrict__ trans, const float* __restrict__ start_t,
    const float* __restrict__ end_t, float* __restrict__ lossp)
{
    const int b = blockIdx.x, tid = threadIdx.x;
    __shared__ float tr[Tn * Tn];
    for (int i = tid; i < Tn * Tn; i += 64) tr[i] = trans[i];
    __syncthreads();
    const int* yb = y + (size_t)b * Sn;
    const float* emb = em + (size_t)b * Sn * Tn;

    float gs = 0.f;
    for (int s2 = tid; s2 < Sn; s2 += 64) gs += emb[s2 * Tn + yb[s2]];
    for (int s2 = tid; s2 < Sn - 1; s2 += 64) gs += tr[yb[s2] * Tn + yb[s2 + 1]];
    #pragma unroll
    for (int o = 32; o > 0; o >>= 1) gs += __shfl_down(gs, o, 64);

    const int jj = (tid < Tn) ? tid : 0;
    float alpha = start_t[jj] + emb[jj];
    for (int s2 = 1; s2 < Sn; ++s2) {
        float av[Tn];
        #pragma unroll
        for (int i = 0; i < Tn; ++i) av[i] = __shfl(alpha, i, 64) + tr[i * Tn + jj];
        float m = av[0];
        #pragma unroll
        for (int i = 1; i < Tn; ++i) m = fmaxf(m, av[i]);
        float ss = 0.f;
        #pragma unroll
        for (int i = 0; i < Tn; ++i) ss += expf(av[i] - m);
        alpha = logf(ss) + m + emb[s2 * Tn + jj];
    }
    const float xv = alpha + end_t[jj];
    float m9 = -1e30f, vv[Tn];
    #pragma unroll
    for (int i = 0; i < Tn; ++i) { vv[i] = __shfl(xv, i, 64); m9 = fmaxf(m9, vv[i]); }
    float s9 = 0.f;
    #pragma unroll
    for (int i = 0; i < Tn; ++i) s9 += expf(vv[i] - m9);
    const float logZ = logf(s9) + m9;
    if (tid == 0) lossp[b] = logZ - (gs + start_t[yb[0]] + end_t[yb[Sn - 1]]);
}

__global__ __launch_bounds__(64) void loss_final(const float* __restrict__ lossp,
                                                 float* __restrict__ out)
{
    float v = lossp[threadIdx.x];
    #pragma unroll
    for (int o = 32; o > 0; o >>= 1) v += __shfl_down(v, o, 64);
    if (threadIdx.x == 0) out[0] = v * (1.f / 64.f);
}

// ---------------- Viterbi decode ----------------
__global__ __launch_bounds__(64) void viterbi_k(
    const float* __restrict__ em, const float* __restrict__ trans,
    const float* __restrict__ start_t, const float* __restrict__ end_t,
    float* __restrict__ out)
{
    const int b = blockIdx.x, tid = threadIdx.x;
    __shared__ float tr[Tn * Tn];
    __shared__ unsigned char bp[Sn - 1][16];
    __shared__ float vfin[Tn];
    for (int i = tid; i < Tn * Tn; i += 64) tr[i] = trans[i];
    __syncthreads();
    const float* emb = em + (size_t)b * Sn * Tn;
    const int jj = (tid < Tn) ? tid : 0;
    float v = start_t[jj] + emb[jj];
    for (int s2 = 1; s2 < Sn; ++s2) {
        float vv[Tn];
        #pragma unroll
        for (int i = 0; i < Tn; ++i) vv[i] = __shfl(v, i, 64);
        float best = -1e30f; int bi = 0;
        #pragma unroll
        for (int i = 0; i < Tn; ++i) {
            const float sc = vv[i] + tr[i * Tn + jj];
            if (sc > best) { best = sc; bi = i; }   // strict > == first-max (np.argmax)
        }
        if (tid < Tn) bp[s2 - 1][tid] = (unsigned char)bi;
        v = best + emb[s2 * Tn + jj];
    }
    if (tid < Tn) vfin[tid] = v + end_t[tid];
    __syncthreads();
    if (tid == 0) {
        float best = -1e30f; int cur = 0;
        for (int i = 0; i < Tn; ++i) if (vfin[i] > best) { best = vfin[i]; cur = i; }
        float* ob = out + 1 + (size_t)b * Sn;
        ob[Sn - 1] = (float)cur;
        for (int s2 = Sn - 1; s2 >= 1; --s2) { cur = bp[s2 - 1][cur]; ob[s2 - 1] = (float)cur; }
    }
}

// ---------------- launch ----------------
extern "C" void kernel_launch(void* const* d_in, const int* in_sizes, int n_in,
                              void* d_out, int out_size, void* d_ws, size_t ws_size,
                              hipStream_t stream)
{
    (void)in_sizes; (void)n_in; (void)out_size; (void)ws_size;
    const float* bert  = (const float*)d_in[0];
    const int*   y     = (const int*)d_in[1];
    const float* Wih   = (const float*)d_in[2];
    const float* Whh   = (const float*)d_in[3];
    const float* bvec  = (const float*)d_in[4];
    const float* fcw   = (const float*)d_in[5];
    const float* fcb   = (const float*)d_in[6];
    const float* trans = (const float*)d_in[7];
    const float* stt   = (const float*)d_in[8];
    const float* ent   = (const float*)d_in[9];
    float* out = (float*)d_out;
    float* ws  = (float*)d_ws;

    float* WihT  = ws + OFF_WIHT;
    float* gates = ws + OFF_GATES;
    float* h1    = ws + OFF_H1;
    float* emP   = ws + OFF_EMP;
    float* em    = ws + OFF_EM;
    float* hbuf  = ws + OFF_HBUF;
    float* cst   = ws + OFF_CST;
    float* lossp = ws + OFF_LP;
    int*   stamps = (int*)(ws + OFF_STAMP);

    init_bar<<<dim3(64), dim3(256), 0, stream>>>(stamps);
    transpose_w<<<dim3(4608), dim3(256), 0, stream>>>(Wih, WihT, Dn, 4 * G4n * Dn);

    // stage 0: layer-0 chunk 0 alone
    gemm_gates<<<dim3(12, 64), dim3(256), 0, stream>>>(bert, WihT, bvec, gates, 0, 0);
    lstm_persist<<<dim3(512), dim3(256), 0, stream>>>(gates, Whh, fcw, h1, emP,
                                                      hbuf, cst, stamps, 0, 0, 0, 0);
    // stages 1..NCH-1: layer-0 chunk c  ||  layer-1 chunk c-1
    for (int c = 1; c < NCH; ++c) {
        gemm_gates<<<dim3(12, 64), dim3(256), 0, stream>>>(bert, WihT, bvec, gates, 0, c);
        gemm_gates<<<dim3(12, 64), dim3(256), 0, stream>>>(h1, WihT, bvec,
                                                           gates + SZ_GCH, 1, c - 1);
        lstm_persist<<<dim3(1024), dim3(256), 0, stream>>>(gates, Whh, fcw, h1, emP,
                                                           hbuf, cst, stamps, 0, c, 1, c - 1);
    }
    // final: layer-1 chunk NCH-1 alone
    gemm_gates<<<dim3(12, 64), dim3(256), 0, stream>>>(h1, WihT, bvec,
                                                       gates + SZ_GCH, 1, NCH - 1);
    lstm_persist<<<dim3(512), dim3(256), 0, stream>>>(gates, Whh, fcw, h1, emP,
                                                      hbuf, cst, stamps, 1, NCH - 1, 0, 0);

    em_combine<<<dim3((Bn * Sn * Tn + 255) / 256), dim3(256), 0, stream>>>(emP, fcb, em);
    crf_loss<<<dim3(Bn), dim3(64), 0, stream>>>(em, y, trans, stt, ent, lossp);
    loss_final<<<dim3(1), dim3(64), 0, stream>>>(lossp, out);
    viterbi_k<<<dim3(Bn), dim3(64), 0, stream>>>(em, trans, stt, ent, out);
}

// Round 10
// 14161.026 us; speedup vs baseline: 2.5259x; 2.5259x over previous
//
#include <hip/hip_runtime.h>

// Problem dims
#define Bn   64
#define Sn   512
#define Dn   768
#define Hn   384
#define G4n  1536   // 4*H
#define Tn   9
#define SCHn 128    // S-chunk
#define NCH  4      // Sn / SCHn

// ---- workspace layout (in floats) ----
#define OFF_WIHT  0ull
#define SZ_WIHT   (4ull * Dn * G4n)                       // 4,718,592
#define OFF_GATES (OFF_WIHT + SZ_WIHT)
#define SZ_GATES  (2ull * Bn * SCHn * G4n)                // 25,165,824
#define OFF_H1    (OFF_GATES + SZ_GATES)
#define SZ_H1     ((unsigned long long)Bn * Sn * Dn)      // 25,165,824
#define OFF_EMP   (OFF_H1 + SZ_H1)
#define SZ_EMP    (2ull * Bn * Sn * Tn)
#define OFF_EM    (OFF_EMP + SZ_EMP)
#define SZ_EM     ((unsigned long long)Bn * Sn * Tn)
#define OFF_HBUF  (OFF_EM + SZ_EM)
#define SZ_HBUF   (2ull * 2 * Bn * Hn)                    // [parity][dir][b][d]
#define OFF_CST   (OFF_HBUF + SZ_HBUF)
#define SZ_CST    (2ull * Bn * Hn)
#define OFF_LP    (OFF_CST + SZ_CST)
#define SZ_LP     64ull
#define OFF_STAMP (OFF_LP + SZ_LP)
// stamps: [L:2][dir:2][bg:8][dg:32] lines of 32 ints; dwords 0/1 = wave0/1 stamps
#define STAMP_TOTAL (2 * 2 * 8 * 32 * 32)

static __device__ __forceinline__ float sigf(float x) { return 1.f / (1.f + expf(-x)); }

// ---- LLC primitives: relaxed system scope (bypass L1/L2, no cache maintenance) ----
static __device__ __forceinline__ unsigned long long llc_load_u64(const unsigned long long* p) {
    return __hip_atomic_load(p, __ATOMIC_RELAXED, __HIP_MEMORY_SCOPE_SYSTEM);
}
static __device__ __forceinline__ void llc_store_f32(float* p, float v) {
    __hip_atomic_store(p, v, __ATOMIC_RELAXED, __HIP_MEMORY_SCOPE_SYSTEM);
}

// ---------------- weight transpose: [ld][N=1536][K] -> [ld][K][N] ----------------
__global__ void transpose_w(const float* __restrict__ in, float* __restrict__ out,
                            int K, int total)
{
    const int nk = G4n * K;
    for (int idx = blockIdx.x * blockDim.x + threadIdx.x; idx < total;
         idx += gridDim.x * blockDim.x) {
        const int ld = idx / nk;
        const int r  = idx - ld * nk;
        const int k  = r / G4n;
        const int n  = r - k * G4n;
        out[idx] = in[(size_t)ld * nk + (size_t)n * K + k];
    }
}

// ---------------- stamp init (every launch: replay-safe) ----------------
__global__ void init_bar(int* __restrict__ st)
{
    for (int i = blockIdx.x * 256 + threadIdx.x; i < STAMP_TOTAL; i += 64 * 256)
        st[i] = 0;
}

// ---------------- gates GEMM: G[m][col'] = A_row(m) . WihT[:,n] + bias[n] ----------------
// col' = (n%384)*4 + n/384  (i,f,g,o interleaved per hidden unit)
__global__ __launch_bounds__(256) void gemm_gates(
    const float* __restrict__ A,      // [64][512][768] (bert or h1)
    const float* __restrict__ WihT,   // [2][2][768][1536]
    const float* __restrict__ bvec,   // [2][2][1536]
    float* __restrict__ G,            // [2][64][128][1536] (col-interleaved)
    int layer, int chunk)
{
    const int tid = threadIdx.x;
    const int nb  = blockIdx.x;       // 0..11
    const int mb  = blockIdx.y;       // 0..127
    const int m0  = mb * 128;
    const int dir = mb >> 6;
    const int n0c = nb * 128;

    __shared__ __align__(16) float As[8][128];
    __shared__ __align__(16) float Bs[8][128];

    const float* BT   = WihT + (size_t)(layer * 2 + dir) * Dn * G4n;
    const float* bias = bvec + (size_t)(layer * 2 + dir) * G4n;

    const int lrow = tid >> 1;            // 0..127
    const int kq   = (tid & 1) * 4;
    const int grow = m0 + lrow;
    const int rem  = grow & 8191;
    const int bb   = rem >> 7;
    const int j    = rem & 127;
    const int p    = chunk * SCHn + j;
    const int s    = dir ? (Sn - 1 - p) : p;
    const float* arow = A + ((size_t)bb * Sn + s) * Dn;

    const int kr = tid >> 5;              // 0..7
    const int nq = (tid & 31) * 4;

    const int tx = tid & 15, ty = tid >> 4;

    float acc[8][8];
    #pragma unroll
    for (int i = 0; i < 8; ++i)
        #pragma unroll
        for (int q = 0; q < 8; ++q) acc[i][q] = 0.f;

    for (int k0 = 0; k0 < Dn; k0 += 8) {
        const float4 av = *(const float4*)(arow + k0 + kq);
        const float4 bv = *(const float4*)(BT + (size_t)(k0 + kr) * G4n + n0c + nq);
        __syncthreads();
        As[kq + 0][lrow] = av.x;
        As[kq + 1][lrow] = av.y;
        As[kq + 2][lrow] = av.z;
        As[kq + 3][lrow] = av.w;
        *(float4*)&Bs[kr][nq] = bv;
        __syncthreads();
        #pragma unroll
        for (int kk = 0; kk < 8; ++kk) {
            float a8[8], b8[8];
            #pragma unroll
            for (int i = 0; i < 8; ++i) a8[i] = As[kk][ty * 8 + i];
            #pragma unroll
            for (int i = 0; i < 8; ++i) b8[i] = Bs[kk][tx * 8 + i];
            #pragma unroll
            for (int i = 0; i < 8; ++i)
                #pragma unroll
                for (int q = 0; q < 8; ++q) acc[i][q] += a8[i] * b8[q];
        }
    }

    float bias8[8];
    #pragma unroll
    for (int q = 0; q < 8; ++q) bias8[q] = bias[n0c + tx * 8 + q];

    #pragma unroll
    for (int i = 0; i < 8; ++i) {
        const int row = m0 + ty * 8 + i;
        float* gr = G + (size_t)row * G4n;
        #pragma unroll
        for (int q = 0; q < 8; ++q) {
            const int n = n0c + tx * 8 + q;
            const int g = n / 384;
            const int d2 = n - g * 384;
            gr[d2 * 4 + g] = acc[i][q] + bias8[q];
        }
    }
}

// ---------------- persistent single-direction LSTM recurrence, one S-chunk ----------------
// grid 512 = (dir:2) x (bg:8 of 8 batches) x (dg:32 of 12 dims); 2 WGs/CU.
// Sync: per-wave stamp dwords (one 128-B line/WG); raw lgkm-only barriers;
// gates prefetch issued after the poll so it never blocks sync detection.
__global__ __launch_bounds__(256, 2) void lstm_persist(
    const float* __restrict__ gates,  // [2][64][128][1536] col-interleaved
    const float* __restrict__ Whh,    // [2][2][1536][384]
    const float* __restrict__ fcw,    // [9][768]
    float* __restrict__ h1,           // [64][512][768]  (layer 0 only)
    float* __restrict__ emP,          // [2][64][512][9] (layer 1 only)
    float* __restrict__ hbuf,         // [parity][dir][64][384]
    float* __restrict__ cst,          // [dir][64][384]
    int* __restrict__ stamps,
    int layer, int chunk)
{
    const int tid = threadIdx.x;
    const int bid = blockIdx.x;
    const int dir = bid >> 8;
    const int bg  = (bid >> 5) & 7;
    const int dg  = bid & 31;
    const int b0 = bg * 8, d0 = dg * 12;

    __shared__ __align__(16) float hstage[8][396];
    __shared__ __align__(16) float red[4][16][28];
    __shared__ float cs[8][12];
    __shared__ float fcwl[Hn];

    const int ct = tid & 15;
    const int kq = tid >> 4;
    const int k0 = kq * 24;
    const int sbb = tid >> 5, skq = tid & 31;
    const bool pw = (tid < 96);
    const int pb = tid / 12, pdd = tid - pb * 12;
    const int lane = tid & 63, wv = tid >> 6;

    int* sgrp = stamps + (((layer * 2 + dir) * 8 + bg) * 32) * 32;
    const unsigned long long* pollp = (const unsigned long long*)(sgrp + skq * 32);

    // ---- Whh slice into registers ----
    float wreg[72];
    {
        const float* Wbase = Whh + (size_t)(layer * 2 + dir) * G4n * Hn;
        #pragma unroll
        for (int c = 0; c < 3; ++c) {
            const int cc = ct * 3 + c;               // col' = dd*4+g
            const int dd = cc >> 2, g = cc & 3;
            const float* wr = Wbase + (size_t)(g * Hn + d0 + dd) * Hn + k0;
            #pragma unroll
            for (int kk = 0; kk < 24; kk += 4) {
                const float4 w4 = *(const float4*)(wr + kk);
                wreg[c * 24 + kk + 0] = w4.x;
                wreg[c * 24 + kk + 1] = w4.y;
                wreg[c * 24 + kk + 2] = w4.z;
                wreg[c * 24 + kk + 3] = w4.w;
            }
        }
    }

    const bool fcwg = (layer == 1) && (dg < Tn);
    if (fcwg) {
        for (int k2 = tid; k2 < Hn; k2 += 256)
            fcwl[k2] = fcw[dg * Dn + dir * Hn + k2];
    }

    if (pw) {
        cs[pb][pdd] = (chunk == 0) ? 0.f
            : cst[((size_t)dir * Bn + b0 + pb) * Hn + d0 + pdd];
    }
    __syncthreads();

    // prologue gates prefetch (first poll will drain it — once per dispatch)
    float4 g4 = make_float4(0.f, 0.f, 0.f, 0.f);
    if (pw)
        g4 = *(const float4*)(gates + ((size_t)(dir * Bn + b0 + pb) * SCHn + 0) * G4n
                              + (d0 + pdd) * 4);

    for (int j = 0; j < SCHn; ++j) {
        const int sg = chunk * SCHn + j;
        const int p_rd = sg & 1, p_wr = (sg + 1) & 1;
        const int s = dir ? (Sn - 1 - sg) : sg;

        // ---- poll producer stamps (both wave-dwords via one u64) + stage h ----
        if (chunk == 0 && j == 0) {
            #pragma unroll
            for (int i = 0; i < 6; ++i)
                *(float2*)&hstage[sbb][skq * 12 + 2 * i] = make_float2(0.f, 0.f);
        } else {
            const int need = sg;     // per-layer tags: producer stamped sg after step sg-1
            unsigned long long sv = llc_load_u64(pollp);
            while ((int)(sv & 0xffffffffu) < need || (int)(sv >> 32) < need) {
                __builtin_amdgcn_s_sleep(1);
                sv = llc_load_u64(pollp);
            }
            const unsigned long long* hsrc = (const unsigned long long*)
                (hbuf + ((size_t)(p_rd * 2 + dir) * Bn + b0 + sbb) * Hn) + skq * 6;
            unsigned long long v[6];
            #pragma unroll
            for (int i = 0; i < 6; ++i) v[i] = llc_load_u64(hsrc + i);
            #pragma unroll
            for (int i = 0; i < 6; ++i) {
                float2 f2;
                f2.x = __uint_as_float((unsigned int)v[i]);
                f2.y = __uint_as_float((unsigned int)(v[i] >> 32));
                *(float2*)&hstage[sbb][skq * 12 + 2 * i] = f2;
            }
        }

        // next step's gates — issued AFTER poll; stays in flight across raw barriers
        float4 g4n = make_float4(0.f, 0.f, 0.f, 0.f);
        if (pw && (j + 1) < SCHn)
            g4n = *(const float4*)(gates
                  + ((size_t)(dir * Bn + b0 + pb) * SCHn + (j + 1)) * G4n
                  + (d0 + pdd) * 4);

        // B: LDS-only drain + barrier (vmem prefetch stays outstanding)
        asm volatile("s_waitcnt lgkmcnt(0)\n\ts_barrier" ::: "memory");

        // ---- recurrent matvec over this thread's k-slice ----
        float acc[24];
        #pragma unroll
        for (int i = 0; i < 24; ++i) acc[i] = 0.f;
        #pragma unroll
        for (int b = 0; b < 8; ++b) {
            const float* hp = &hstage[b][k0];
            float hv[24];
            #pragma unroll
            for (int i = 0; i < 6; ++i) {
                const float4 h4 = *(const float4*)(hp + i * 4);
                hv[i * 4 + 0] = h4.x; hv[i * 4 + 1] = h4.y;
                hv[i * 4 + 2] = h4.z; hv[i * 4 + 3] = h4.w;
            }
            #pragma unroll
            for (int c = 0; c < 3; ++c)
                #pragma unroll
                for (int kk = 0; kk < 24; ++kk)
                    acc[b * 3 + c] += hv[kk] * wreg[c * 24 + kk];
        }
        #pragma unroll
        for (int i = 0; i < 24; ++i) {
            acc[i] += __shfl_xor(acc[i], 16);
            acc[i] += __shfl_xor(acc[i], 32);
        }
        if (lane < 16) {
            #pragma unroll
            for (int i = 0; i < 24; i += 4) {
                float4 t4; t4.x = acc[i]; t4.y = acc[i + 1];
                t4.z = acc[i + 2]; t4.w = acc[i + 3];
                *(float4*)&red[wv][lane][i] = t4;
            }
        }

        // fused FC for step sg-1: hstage holds that step's OUTPUT h
        if (fcwg && j >= 1) {
            const int sgp = sg - 1;
            const int sprev = dir ? (Sn - 1 - sgp) : sgp;
            const float* hp2 = &hstage[sbb][skq * 12];
            const float* wp2 = &fcwl[skq * 12];
            float e2 = 0.f;
            #pragma unroll
            for (int q = 0; q < 12; ++q) e2 += hp2[q] * wp2[q];
            e2 += __shfl_down(e2, 16, 32);
            e2 += __shfl_down(e2, 8, 32);
            e2 += __shfl_down(e2, 4, 32);
            e2 += __shfl_down(e2, 2, 32);
            e2 += __shfl_down(e2, 1, 32);
            if (skq == 0)
                emP[((size_t)(dir * Bn + b0 + sbb) * Sn + sprev) * Tn + dg] = e2;
        }

        // C: red ready (LDS-only drain)
        asm volatile("s_waitcnt lgkmcnt(0)\n\ts_barrier" ::: "memory");

        // ---- final sum + pointwise ----
        if (pw) {
            float pre[4];
            #pragma unroll
            for (int g = 0; g < 4; ++g) {
                const int cc = pdd * 4 + g;
                const int ct2 = cc / 3;
                const int e = pb * 3 + (cc - ct2 * 3);
                pre[g] = red[0][ct2][e] + red[1][ct2][e]
                       + red[2][ct2][e] + red[3][ct2][e];
            }
            const float ii = sigf(pre[0] + g4.x);
            const float ff = sigf(pre[1] + g4.y);
            const float gg = tanhf(pre[2] + g4.z);
            const float oo = sigf(pre[3] + g4.w);
            const float cn = ff * cs[pb][pdd] + ii * gg;
            cs[pb][pdd] = cn;
            const float hn = oo * tanhf(cn);
            llc_store_f32(&hbuf[((size_t)(p_wr * 2 + dir) * Bn + b0 + pb) * Hn + d0 + pdd], hn);
            if (layer == 0)
                h1[((size_t)(b0 + pb) * Sn + s) * Dn + dir * Hn + d0 + pdd] = hn;
        }
        // per-wave arrive: only waves 0,1 hold h stores; drain own vmem, stamp own dword
        if (tid < 128) {
            asm volatile("s_waitcnt vmcnt(0)" ::: "memory");
            if ((tid & 63) == 0)
                __hip_atomic_store(sgrp + dg * 32 + (tid >> 6), sg + 1,
                                   __ATOMIC_RELAXED, __HIP_MEMORY_SCOPE_SYSTEM);
        }
        g4 = g4n;
    }

    // ---- epilogue: FC for this chunk's last step (layer 1) ----
    if (fcwg) {
        const int sgl = chunk * SCHn + SCHn - 1;
        const int need = sgl + 1;
        unsigned long long sv = llc_load_u64(pollp);
        while ((int)(sv & 0xffffffffu) < need || (int)(sv >> 32) < need) {
            __builtin_amdgcn_s_sleep(1);
            sv = llc_load_u64(pollp);
        }
        const int pp = (sgl + 1) & 1;
        const unsigned long long* hsrc = (const unsigned long long*)
            (hbuf + ((size_t)(pp * 2 + dir) * Bn + b0 + sbb) * Hn) + skq * 6;
        unsigned long long v[6];
        #pragma unroll
        for (int i = 0; i < 6; ++i) v[i] = llc_load_u64(hsrc + i);
        #pragma unroll
        for (int i = 0; i < 6; ++i) {
            float2 f2;
            f2.x = __uint_as_float((unsigned int)v[i]);
            f2.y = __uint_as_float((unsigned int)(v[i] >> 32));
            *(float2*)&hstage[sbb][skq * 12 + 2 * i] = f2;
        }
        __syncthreads();
        const int sprev = dir ? (Sn - 1 - sgl) : sgl;
        const float* hp2 = &hstage[sbb][skq * 12];
        const float* wp2 = &fcwl[skq * 12];
        float e2 = 0.f;
        #pragma unroll
        for (int q = 0; q < 12; ++q) e2 += hp2[q] * wp2[q];
        e2 += __shfl_down(e2, 16, 32);
        e2 += __shfl_down(e2, 8, 32);
        e2 += __shfl_down(e2, 4, 32);
        e2 += __shfl_down(e2, 2, 32);
        e2 += __shfl_down(e2, 1, 32);
        if (skq == 0)
            emP[((size_t)(dir * Bn + b0 + sbb) * Sn + sprev) * Tn + dg] = e2;
    }

    if (pw)
        cst[((size_t)dir * Bn + b0 + pb) * Hn + d0 + pdd] = cs[pb][pdd];
}

// ---------------- emission combine ----------------
__global__ void em_combine(const float* __restrict__ emP, const float* __restrict__ fcb,
                           float* __restrict__ em)
{
    const int idx = blockIdx.x * 256 + threadIdx.x;
    if (idx < Bn * Sn * Tn) {
        const int t = idx % Tn;
        em[idx] = emP[idx] + emP[(size_t)Bn * Sn * Tn + idx] + fcb[t];
    }
}

// ---------------- CRF negative log-likelihood ----------------
__global__ __launch_bounds__(64) void crf_loss(
    const float* __restrict__ em, const int* __restrict__ y,
    const float* __restrict__ trans, const float* __restrict__ start_t,
    const float* __restrict__ end_t, float* __restrict__ lossp)
{
    const int b = blockIdx.x, tid = threadIdx.x;
    __shared__ float tr[Tn * Tn];
    for (int i = tid; i < Tn * Tn; i += 64) tr[i] = trans[i];
    __syncthreads();
    const int* yb = y + (size_t)b * Sn;
    const float* emb = em + (size_t)b * Sn * Tn;

    float gs = 0.f;
    for (int s2 = tid; s2 < Sn; s2 += 64) gs += emb[s2 * Tn + yb[s2]];
    for (int s2 = tid; s2 < Sn - 1; s2 += 64) gs += tr[yb[s2] * Tn + yb[s2 + 1]];
    #pragma unroll
    for (int o = 32; o > 0; o >>= 1) gs += __shfl_down(gs, o, 64);

    const int jj = (tid < Tn) ? tid : 0;
    float alpha = start_t[jj] + emb[jj];
    for (int s2 = 1; s2 < Sn; ++s2) {
        float av[Tn];
        #pragma unroll
        for (int i = 0; i < Tn; ++i) av[i] = __shfl(alpha, i, 64) + tr[i * Tn + jj];
        float m = av[0];
        #pragma unroll
        for (int i = 1; i < Tn; ++i) m = fmaxf(m, av[i]);
        float ss = 0.f;
        #pragma unroll
        for (int i = 0; i < Tn; ++i) ss += expf(av[i] - m);
        alpha = logf(ss) + m + emb[s2 * Tn + jj];
    }
    const float xv = alpha + end_t[jj];
    float m9 = -1e30f, vv[Tn];
    #pragma unroll
    for (int i = 0; i < Tn; ++i) { vv[i] = __shfl(xv, i, 64); m9 = fmaxf(m9, vv[i]); }
    float s9 = 0.f;
    #pragma unroll
    for (int i = 0; i < Tn; ++i) s9 += expf(vv[i] - m9);
    const float logZ = logf(s9) + m9;
    if (tid == 0) lossp[b] = logZ - (gs + start_t[yb[0]] + end_t[yb[Sn - 1]]);
}

__global__ __launch_bounds__(64) void loss_final(const float* __restrict__ lossp,
                                                 float* __restrict__ out)
{
    float v = lossp[threadIdx.x];
    #pragma unroll
    for (int o = 32; o > 0; o >>= 1) v += __shfl_down(v, o, 64);
    if (threadIdx.x == 0) out[0] = v * (1.f / 64.f);
}

// ---------------- Viterbi decode ----------------
__global__ __launch_bounds__(64) void viterbi_k(
    const float* __restrict__ em, const float* __restrict__ trans,
    const float* __restrict__ start_t, const float* __restrict__ end_t,
    float* __restrict__ out)
{
    const int b = blockIdx.x, tid = threadIdx.x;
    __shared__ float tr[Tn * Tn];
    __shared__ unsigned char bp[Sn - 1][16];
    __shared__ float vfin[Tn];
    for (int i = tid; i < Tn * Tn; i += 64) tr[i] = trans[i];
    __syncthreads();
    const float* emb = em + (size_t)b * Sn * Tn;
    const int jj = (tid < Tn) ? tid : 0;
    float v = start_t[jj] + emb[jj];
    for (int s2 = 1; s2 < Sn; ++s2) {
        float vv[Tn];
        #pragma unroll
        for (int i = 0; i < Tn; ++i) vv[i] = __shfl(v, i, 64);
        float best = -1e30f; int bi = 0;
        #pragma unroll
        for (int i = 0; i < Tn; ++i) {
            const float sc = vv[i] + tr[i * Tn + jj];
            if (sc > best) { best = sc; bi = i; }   // strict > == first-max (np.argmax)
        }
        if (tid < Tn) bp[s2 - 1][tid] = (unsigned char)bi;
        v = best + emb[s2 * Tn + jj];
    }
    if (tid < Tn) vfin[tid] = v + end_t[tid];
    __syncthreads();
    if (tid == 0) {
        float best = -1e30f; int cur = 0;
        for (int i = 0; i < Tn; ++i) if (vfin[i] > best) { best = vfin[i]; cur = i; }
        float* ob = out + 1 + (size_t)b * Sn;
        ob[Sn - 1] = (float)cur;
        for (int s2 = Sn - 1; s2 >= 1; --s2) { cur = bp[s2 - 1][cur]; ob[s2 - 1] = (float)cur; }
    }
}

// ---------------- launch ----------------
extern "C" void kernel_launch(void* const* d_in, const int* in_sizes, int n_in,
                              void* d_out, int out_size, void* d_ws, size_t ws_size,
                              hipStream_t stream)
{
    (void)in_sizes; (void)n_in; (void)out_size; (void)ws_size;
    const float* bert  = (const float*)d_in[0];
    const int*   y     = (const int*)d_in[1];
    const float* Wih   = (const float*)d_in[2];
    const float* Whh   = (const float*)d_in[3];
    const float* bvec  = (const float*)d_in[4];
    const float* fcw   = (const float*)d_in[5];
    const float* fcb   = (const float*)d_in[6];
    const float* trans = (const float*)d_in[7];
    const float* stt   = (const float*)d_in[8];
    const float* ent   = (const float*)d_in[9];
    float* out = (float*)d_out;
    float* ws  = (float*)d_ws;

    float* WihT  = ws + OFF_WIHT;
    float* gates = ws + OFF_GATES;
    float* h1    = ws + OFF_H1;
    float* emP   = ws + OFF_EMP;
    float* em    = ws + OFF_EM;
    float* hbuf  = ws + OFF_HBUF;
    float* cst   = ws + OFF_CST;
    float* lossp = ws + OFF_LP;
    int*   stamps = (int*)(ws + OFF_STAMP);

    init_bar<<<dim3(64), dim3(256), 0, stream>>>(stamps);
    transpose_w<<<dim3(4608), dim3(256), 0, stream>>>(Wih, WihT, Dn, 4 * G4n * Dn);

    for (int l = 0; l < 2; ++l) {
        const float* A = (l == 0) ? bert : h1;
        for (int c = 0; c < NCH; ++c) {
            gemm_gates<<<dim3(12, 128), dim3(256), 0, stream>>>(A, WihT, bvec, gates, l, c);
            lstm_persist<<<dim3(512), dim3(256), 0, stream>>>(gates, Whh, fcw, h1, emP,
                                                              hbuf, cst, stamps, l, c);
        }
    }

    em_combine<<<dim3((Bn * Sn * Tn + 255) / 256), dim3(256), 0, stream>>>(emP, fcb, em);
    crf_loss<<<dim3(Bn), dim3(64), 0, stream>>>(em, y, trans, stt, ent, lossp);
    loss_final<<<dim3(1), dim3(64), 0, stream>>>(lossp, out);
    viterbi_k<<<dim3(Bn), dim3(64), 0, stream>>>(em, trans, stt, ent, out);
}

// Round 11
// 9270.673 us; speedup vs baseline: 3.8584x; 1.5275x over previous
//
#include <hip/hip_runtime.h>

// Problem dims
#define Bn   64
#define Sn   512
#define Dn   768
#define Hn   384
#define G4n  1536   // 4*H
#define Tn   9
#define SCHn 128    // S-chunk
#define NCH  4      // Sn / SCHn

// ---- workspace layout (in float units) ----
#define OFF_WIHB  0ull
#define SZ_WIHB   (2ull * Dn * G4n)                       // 4 slices of [1536][768] ushort
#define OFF_GATES (OFF_WIHB + SZ_WIHB)
#define SZ_GATES  (2ull * Bn * SCHn * G4n)                // 25,165,824
#define OFF_H1B   (OFF_GATES + SZ_GATES)
#define SZ_H1B    ((unsigned long long)Bn * Sn * Dn / 2)  // ushort
#define OFF_BERTB (OFF_H1B + SZ_H1B)
#define SZ_BERTB  ((unsigned long long)Bn * Sn * Dn / 2)  // ushort
#define OFF_EMP   (OFF_BERTB + SZ_BERTB)
#define SZ_EMP    (2ull * Bn * Sn * Tn)
#define OFF_EM    (OFF_EMP + SZ_EMP)
#define SZ_EM     ((unsigned long long)Bn * Sn * Tn)
#define OFF_HBUF  (OFF_EM + SZ_EM)
#define SZ_HBUF   (2ull * 2 * Bn * Hn)                    // [parity][dir][b][d]
#define OFF_CST   (OFF_HBUF + SZ_HBUF)
#define SZ_CST    (2ull * Bn * Hn)
#define OFF_LP    (OFF_CST + SZ_CST)
#define SZ_LP     64ull
#define OFF_STAMP (OFF_LP + SZ_LP)
// stamps: [dir:2][bg:8][dg:32] lines of 32 ints (128B each); tag = layer*Sn+sg+1
#define STAMP_TOTAL (2 * 8 * 32 * 32)

typedef __attribute__((ext_vector_type(8))) short short8v;
typedef __attribute__((ext_vector_type(8))) unsigned short ushort8v;
typedef __attribute__((ext_vector_type(4))) float f32x4;

static __device__ __forceinline__ float sigf(float x) { return 1.f / (1.f + expf(-x)); }

static __device__ __forceinline__ unsigned short f2bf(float x) {
    unsigned u = __float_as_uint(x);
    u += 0x7fffu + ((u >> 16) & 1u);   // RNE
    return (unsigned short)(u >> 16);
}

// ---- LLC primitives: relaxed system scope ----
static __device__ __forceinline__ unsigned long long llc_load_u64(const unsigned long long* p) {
    return __hip_atomic_load(p, __ATOMIC_RELAXED, __HIP_MEMORY_SCOPE_SYSTEM);
}
static __device__ __forceinline__ void llc_store_f32(float* p, float v) {
    __hip_atomic_store(p, v, __ATOMIC_RELAXED, __HIP_MEMORY_SCOPE_SYSTEM);
}
static __device__ __forceinline__ int llc_load_i32(const int* p) {
    return __hip_atomic_load(p, __ATOMIC_RELAXED, __HIP_MEMORY_SCOPE_SYSTEM);
}

// ---------------- fp32 -> bf16 convert ----------------
__global__ void to_bf16(const float* __restrict__ in, unsigned short* __restrict__ out,
                        int total)
{
    for (int i = blockIdx.x * 256 + threadIdx.x; i < total; i += gridDim.x * 256)
        out[i] = f2bf(in[i]);
}

// ---------------- stamp init ----------------
__global__ void init_bar(int* __restrict__ st)
{
    const int i = blockIdx.x * 256 + threadIdx.x;
    if (i < STAMP_TOTAL) st[i] = 0;
}

// ---------------- gates GEMM (bf16 MFMA): G[m][col'] = A_row(m) . Wih^T[:,n] + b[n] ----------------
// col' = (n%384)*4 + n/384. Tile 128x128, BK=32, 4 waves of 64x64.
__global__ __launch_bounds__(256) void gemm_gates(
    const unsigned short* __restrict__ Abf,   // [64][512][768] bf16 (bertbf or h1b)
    const unsigned short* __restrict__ Wb,    // [2][2][1536][768] bf16 (native layout)
    const float* __restrict__ bvec,           // [2][2][1536]
    float* __restrict__ G,                    // [2][64][128][1536] col-interleaved
    int layer, int chunk)
{
    const int tid = threadIdx.x;
    const int nb  = blockIdx.x;       // 0..11
    const int mb  = blockIdx.y;       // 0..127
    const int m0  = mb * 128;
    const int dir = mb >> 6;
    const int n0c = nb * 128;

    __shared__ unsigned short As[128][40];
    __shared__ unsigned short Bs[128][40];

    const unsigned short* BT = Wb + (size_t)(layer * 2 + dir) * G4n * Dn;
    const float* bias = bvec + (size_t)(layer * 2 + dir) * G4n;

    // staging mapping: thread -> (row, 16-elem segment)
    const int mm   = tid >> 1;
    const int seg  = (tid & 1) * 16;
    const int rem  = (m0 + mm) & 8191;
    const int bb   = rem >> 7;
    const int j    = rem & 127;
    const int p    = chunk * SCHn + j;
    const int s    = dir ? (Sn - 1 - p) : p;
    const unsigned short* arow = Abf + ((size_t)bb * Sn + s) * Dn;
    const unsigned short* brow = BT + (size_t)(n0c + mm) * Dn;

    const int l = tid & 63, wave = tid >> 6;
    const int wy = wave >> 1, wx = wave & 1;
    const int fr = l & 15, fk = (l >> 4) * 8;

    f32x4 acc[4][4];
    #pragma unroll
    for (int mt = 0; mt < 4; ++mt)
        #pragma unroll
        for (int nt = 0; nt < 4; ++nt)
            acc[mt][nt] = (f32x4){0.f, 0.f, 0.f, 0.f};

    for (int k0 = 0; k0 < Dn; k0 += 32) {
        const ushort8v a0 = *(const ushort8v*)(arow + k0 + seg);
        const ushort8v a1 = *(const ushort8v*)(arow + k0 + seg + 8);
        const ushort8v b0 = *(const ushort8v*)(brow + k0 + seg);
        const ushort8v b1 = *(const ushort8v*)(brow + k0 + seg + 8);
        __syncthreads();
        *(ushort8v*)&As[mm][seg]     = a0;
        *(ushort8v*)&As[mm][seg + 8] = a1;
        *(ushort8v*)&Bs[mm][seg]     = b0;
        *(ushort8v*)&Bs[mm][seg + 8] = b1;
        __syncthreads();

        short8v af[4], bf[4];
        #pragma unroll
        for (int mt = 0; mt < 4; ++mt)
            af[mt] = *(const short8v*)&As[wy * 64 + mt * 16 + fr][fk];
        #pragma unroll
        for (int nt = 0; nt < 4; ++nt)
            bf[nt] = *(const short8v*)&Bs[wx * 64 + nt * 16 + fr][fk];
        #pragma unroll
        for (int mt = 0; mt < 4; ++mt)
            #pragma unroll
            for (int nt = 0; nt < 4; ++nt)
                acc[mt][nt] = __builtin_amdgcn_mfma_f32_16x16x32_bf16(
                    af[mt], bf[nt], acc[mt][nt], 0, 0, 0);
    }

    // epilogue: bias + col-interleave store
    #pragma unroll
    for (int nt = 0; nt < 4; ++nt) {
        const int n  = n0c + wx * 64 + nt * 16 + fr;
        const int g  = n / 384;
        const int d2 = n - g * 384;
        const int gcol = d2 * 4 + g;
        const float bv = bias[n];
        #pragma unroll
        for (int mt = 0; mt < 4; ++mt) {
            #pragma unroll
            for (int q = 0; q < 4; ++q) {
                const int row = m0 + wy * 64 + mt * 16 + (l >> 4) * 4 + q;
                G[(size_t)row * G4n + gcol] = acc[mt][nt][q] + bv;
            }
        }
    }
}

// ---------------- persistent single-direction LSTM recurrence, one S-chunk ----------------
// (round-8 configuration: grid 512, 2 WGs/CU, per-lane poll, __syncthreads, tid0 stamp)
__global__ __launch_bounds__(256, 2) void lstm_persist(
    const float* __restrict__ gates,  // [2][64][128][1536] col-interleaved
    const float* __restrict__ Whh,    // [2][2][1536][384]
    const float* __restrict__ fcw,    // [9][768]
    unsigned short* __restrict__ h1b, // [64][512][768] bf16 (layer 0 only)
    float* __restrict__ emP,          // [2][64][512][9] (layer 1 only)
    float* __restrict__ hbuf,         // [parity][dir][64][384]
    float* __restrict__ cst,          // [dir][64][384]
    int* __restrict__ stamps,
    int layer, int chunk)
{
    const int tid = threadIdx.x;
    const int bid = blockIdx.x;
    const int dir = bid >> 8;
    const int bg  = (bid >> 5) & 7;
    const int dg  = bid & 31;
    const int b0 = bg * 8, d0 = dg * 12;

    __shared__ __align__(16) float hstage[8][396];
    __shared__ __align__(16) float red[4][16][28];
    __shared__ float cs[8][12];
    __shared__ float fcwl[Hn];

    const int ct = tid & 15;
    const int kq = tid >> 4;
    const int k0 = kq * 24;
    const int sbb = tid >> 5, skq = tid & 31;
    const bool pw = (tid < 96);
    const int pb = tid / 12, pdd = tid - pb * 12;
    const int lane = tid & 63, wv = tid >> 6;

    // ---- Whh slice into registers ----
    float wreg[72];
    {
        const float* Wbase = Whh + (size_t)(layer * 2 + dir) * G4n * Hn;
        #pragma unroll
        for (int c = 0; c < 3; ++c) {
            const int cc = ct * 3 + c;               // col' = dd*4+g
            const int dd = cc >> 2, g = cc & 3;
            const float* wr = Wbase + (size_t)(g * Hn + d0 + dd) * Hn + k0;
            #pragma unroll
            for (int kk = 0; kk < 24; kk += 4) {
                const float4 w4 = *(const float4*)(wr + kk);
                wreg[c * 24 + kk + 0] = w4.x;
                wreg[c * 24 + kk + 1] = w4.y;
                wreg[c * 24 + kk + 2] = w4.z;
                wreg[c * 24 + kk + 3] = w4.w;
            }
        }
    }

    const bool fcwg = (layer == 1) && (dg < Tn);
    if (fcwg) {
        for (int k2 = tid; k2 < Hn; k2 += 256)
            fcwl[k2] = fcw[dg * Dn + dir * Hn + k2];
    }

    if (pw) {
        cs[pb][pdd] = (chunk == 0) ? 0.f
            : cst[((size_t)dir * Bn + b0 + pb) * Hn + d0 + pdd];
    }
    __syncthreads();

    const int* mystamps = stamps + ((dir * 8 + bg) * 32 + skq) * 32;

    for (int j = 0; j < SCHn; ++j) {
        const int sg = chunk * SCHn + j;
        const int p_rd = sg & 1, p_wr = (sg + 1) & 1;
        const int s = dir ? (Sn - 1 - sg) : sg;

        // input gates for this step (latency hides under poll/stage)
        float4 g4 = make_float4(0.f, 0.f, 0.f, 0.f);
        if (pw)
            g4 = *(const float4*)(gates +
                  (((size_t)(dir * Bn + b0 + pb) * SCHn + j) * G4n) + (d0 + pdd) * 4);

        // ---- fused per-lane poll + h load + stage ----
        if (chunk == 0 && j == 0) {
            #pragma unroll
            for (int i = 0; i < 6; ++i)
                *(float2*)&hstage[sbb][skq * 12 + 2 * i] = make_float2(0.f, 0.f);
        } else {
            const int need = layer * Sn + sg;
            while (llc_load_i32(mystamps) < need) __builtin_amdgcn_s_sleep(1);
            const unsigned long long* hsrc = (const unsigned long long*)
                (hbuf + ((size_t)(p_rd * 2 + dir) * Bn + b0 + sbb) * Hn) + skq * 6;
            #pragma unroll
            for (int i = 0; i < 6; ++i) {
                const unsigned long long v = llc_load_u64(hsrc + i);
                float2 f2;
                f2.x = __uint_as_float((unsigned int)v);
                f2.y = __uint_as_float((unsigned int)(v >> 32));
                *(float2*)&hstage[sbb][skq * 12 + 2 * i] = f2;
            }
        }
        __syncthreads();   // B: hstage ready

        // ---- recurrent matvec over this thread's k-slice ----
        float acc[24];
        #pragma unroll
        for (int i = 0; i < 24; ++i) acc[i] = 0.f;
        #pragma unroll
        for (int b = 0; b < 8; ++b) {
            const float* hp = &hstage[b][k0];
            float hv[24];
            #pragma unroll
            for (int i = 0; i < 6; ++i) {
                const float4 h4 = *(const float4*)(hp + i * 4);
                hv[i * 4 + 0] = h4.x; hv[i * 4 + 1] = h4.y;
                hv[i * 4 + 2] = h4.z; hv[i * 4 + 3] = h4.w;
            }
            #pragma unroll
            for (int c = 0; c < 3; ++c)
                #pragma unroll
                for (int kk = 0; kk < 24; ++kk)
                    acc[b * 3 + c] += hv[kk] * wreg[c * 24 + kk];
        }
        #pragma unroll
        for (int i = 0; i < 24; ++i) {
            acc[i] += __shfl_xor(acc[i], 16);
            acc[i] += __shfl_xor(acc[i], 32);
        }
        if (lane < 16) {
            #pragma unroll
            for (int i = 0; i < 24; i += 4) {
                float4 t4; t4.x = acc[i]; t4.y = acc[i + 1];
                t4.z = acc[i + 2]; t4.w = acc[i + 3];
                *(float4*)&red[wv][lane][i] = t4;
            }
        }

        // fused FC for step sg-1: hstage holds that step's OUTPUT h
        if (fcwg && j >= 1) {
            const int sgp = sg - 1;
            const int sprev = dir ? (Sn - 1 - sgp) : sgp;
            const float* hp2 = &hstage[sbb][skq * 12];
            const float* wp2 = &fcwl[skq * 12];
            float e2 = 0.f;
            #pragma unroll
            for (int q = 0; q < 12; ++q) e2 += hp2[q] * wp2[q];
            e2 += __shfl_down(e2, 16, 32);
            e2 += __shfl_down(e2, 8, 32);
            e2 += __shfl_down(e2, 4, 32);
            e2 += __shfl_down(e2, 2, 32);
            e2 += __shfl_down(e2, 1, 32);
            if (skq == 0)
                emP[((size_t)(dir * Bn + b0 + sbb) * Sn + sprev) * Tn + dg] = e2;
        }
        __syncthreads();   // C: red ready, hstage readers done

        // ---- final sum + pointwise ----
        if (pw) {
            float pre[4];
            #pragma unroll
            for (int g = 0; g < 4; ++g) {
                const int cc = pdd * 4 + g;
                const int ct2 = cc / 3;
                const int e = pb * 3 + (cc - ct2 * 3);
                pre[g] = red[0][ct2][e] + red[1][ct2][e]
                       + red[2][ct2][e] + red[3][ct2][e];
            }
            const float ii = sigf(pre[0] + g4.x);
            const float ff = sigf(pre[1] + g4.y);
            const float gg = tanhf(pre[2] + g4.z);
            const float oo = sigf(pre[3] + g4.w);
            const float cn = ff * cs[pb][pdd] + ii * gg;
            cs[pb][pdd] = cn;
            const float hn = oo * tanhf(cn);
            llc_store_f32(&hbuf[((size_t)(p_wr * 2 + dir) * Bn + b0 + pb) * Hn + d0 + pdd], hn);
            if (layer == 0)
                h1b[((size_t)(b0 + pb) * Sn + s) * Dn + dir * Hn + d0 + pdd] = f2bf(hn);
        }
        __syncthreads();   // D: drain stores before stamp
        if (tid == 0)
            __hip_atomic_store(stamps + ((dir * 8 + bg) * 32 + dg) * 32,
                               layer * Sn + sg + 1, __ATOMIC_RELAXED,
                               __HIP_MEMORY_SCOPE_SYSTEM);
    }

    // ---- epilogue: FC for this chunk's last step (layer 1) ----
    if (fcwg) {
        const int sgl = chunk * SCHn + SCHn - 1;
        const int need = layer * Sn + sgl + 1;
        while (llc_load_i32(mystamps) < need) __builtin_amdgcn_s_sleep(1);
        const int pp = (sgl + 1) & 1;
        const unsigned long long* hsrc = (const unsigned long long*)
            (hbuf + ((size_t)(pp * 2 + dir) * Bn + b0 + sbb) * Hn) + skq * 6;
        #pragma unroll
        for (int i = 0; i < 6; ++i) {
            const unsigned long long v = llc_load_u64(hsrc + i);
            float2 f2;
            f2.x = __uint_as_float((unsigned int)v);
            f2.y = __uint_as_float((unsigned int)(v >> 32));
            *(float2*)&hstage[sbb][skq * 12 + 2 * i] = f2;
        }
        __syncthreads();
        const int sprev = dir ? (Sn - 1 - sgl) : sgl;
        const float* hp2 = &hstage[sbb][skq * 12];
        const float* wp2 = &fcwl[skq * 12];
        float e2 = 0.f;
        #pragma unroll
        for (int q = 0; q < 12; ++q) e2 += hp2[q] * wp2[q];
        e2 += __shfl_down(e2, 16, 32);
        e2 += __shfl_down(e2, 8, 32);
        e2 += __shfl_down(e2, 4, 32);
        e2 += __shfl_down(e2, 2, 32);
        e2 += __shfl_down(e2, 1, 32);
        if (skq == 0)
            emP[((size_t)(dir * Bn + b0 + sbb) * Sn + sprev) * Tn + dg] = e2;
    }

    if (pw)
        cst[((size_t)dir * Bn + b0 + pb) * Hn + d0 + pdd] = cs[pb][pdd];
}

// ---------------- emission combine ----------------
__global__ void em_combine(const float* __restrict__ emP, const float* __restrict__ fcb,
                           float* __restrict__ em)
{
    const int idx = blockIdx.x * 256 + threadIdx.x;
    if (idx < Bn * Sn * Tn) {
        const int t = idx % Tn;
        em[idx] = emP[idx] + emP[(size_t)Bn * Sn * Tn + idx] + fcb[t];
    }
}

// ---------------- CRF negative log-likelihood ----------------
__global__ __launch_bounds__(64) void crf_loss(
    const float* __restrict__ em, const int* __restrict__ y,
    const float* __restrict__ trans, const float* __restrict__ start_t,
    const float* __restrict__ end_t, float* __restrict__ lossp)
{
    const int b = blockIdx.x, tid = threadIdx.x;
    __shared__ float tr[Tn * Tn];
    for (int i = tid; i < Tn * Tn; i += 64) tr[i] = trans[i];
    __syncthreads();
    const int* yb = y + (size_t)b * Sn;
    const float* emb = em + (size_t)b * Sn * Tn;

    float gs = 0.f;
    for (int s2 = tid; s2 < Sn; s2 += 64) gs += emb[s2 * Tn + yb[s2]];
    for (int s2 = tid; s2 < Sn - 1; s2 += 64) gs += tr[yb[s2] * Tn + yb[s2 + 1]];
    #pragma unroll
    for (int o = 32; o > 0; o >>= 1) gs += __shfl_down(gs, o, 64);

    const int jj = (tid < Tn) ? tid : 0;
    float alpha = start_t[jj] + emb[jj];
    for (int s2 = 1; s2 < Sn; ++s2) {
        float av[Tn];
        #pragma unroll
        for (int i = 0; i < Tn; ++i) av[i] = __shfl(alpha, i, 64) + tr[i * Tn + jj];
        float m = av[0];
        #pragma unroll
        for (int i = 1; i < Tn; ++i) m = fmaxf(m, av[i]);
        float ss = 0.f;
        #pragma unroll
        for (int i = 0; i < Tn; ++i) ss += expf(av[i] - m);
        alpha = logf(ss) + m + emb[s2 * Tn + jj];
    }
    const float xv = alpha + end_t[jj];
    float m9 = -1e30f, vv[Tn];
    #pragma unroll
    for (int i = 0; i < Tn; ++i) { vv[i] = __shfl(xv, i, 64); m9 = fmaxf(m9, vv[i]); }
    float s9 = 0.f;
    #pragma unroll
    for (int i = 0; i < Tn; ++i) s9 += expf(vv[i] - m9);
    const float logZ = logf(s9) + m9;
    if (tid == 0) lossp[b] = logZ - (gs + start_t[yb[0]] + end_t[yb[Sn - 1]]);
}

__global__ __launch_bounds__(64) void loss_final(const float* __restrict__ lossp,
                                                 float* __restrict__ out)
{
    float v = lossp[threadIdx.x];
    #pragma unroll
    for (int o = 32; o > 0; o >>= 1) v += __shfl_down(v, o, 64);
    if (threadIdx.x == 0) out[0] = v * (1.f / 64.f);
}

// ---------------- Viterbi decode ----------------
__global__ __launch_bounds__(64) void viterbi_k(
    const float* __restrict__ em, const float* __restrict__ trans,
    const float* __restrict__ start_t, const float* __restrict__ end_t,
    float* __restrict__ out)
{
    const int b = blockIdx.x, tid = threadIdx.x;
    __shared__ float tr[Tn * Tn];
    __shared__ unsigned char bp[Sn - 1][16];
    __shared__ float vfin[Tn];
    for (int i = tid; i < Tn * Tn; i += 64) tr[i] = trans[i];
    __syncthreads();
    const float* emb = em + (size_t)b * Sn * Tn;
    const int jj = (tid < Tn) ? tid : 0;
    float v = start_t[jj] + emb[jj];
    for (int s2 = 1; s2 < Sn; ++s2) {
        float vv[Tn];
        #pragma unroll
        for (int i = 0; i < Tn; ++i) vv[i] = __shfl(v, i, 64);
        float best = -1e30f; int bi = 0;
        #pragma unroll
        for (int i = 0; i < Tn; ++i) {
            const float sc = vv[i] + tr[i * Tn + jj];
            if (sc > best) { best = sc; bi = i; }   // strict > == first-max (np.argmax)
        }
        if (tid < Tn) bp[s2 - 1][tid] = (unsigned char)bi;
        v = best + emb[s2 * Tn + jj];
    }
    if (tid < Tn) vfin[tid] = v + end_t[tid];
    __syncthreads();
    if (tid == 0) {
        float best = -1e30f; int cur = 0;
        for (int i = 0; i < Tn; ++i) if (vfin[i] > best) { best = vfin[i]; cur = i; }
        float* ob = out + 1 + (size_t)b * Sn;
        ob[Sn - 1] = (float)cur;
        for (int s2 = Sn - 1; s2 >= 1; --s2) { cur = bp[s2 - 1][cur]; ob[s2 - 1] = (float)cur; }
    }
}

// ---------------- launch ----------------
extern "C" void kernel_launch(void* const* d_in, const int* in_sizes, int n_in,
                              void* d_out, int out_size, void* d_ws, size_t ws_size,
                              hipStream_t stream)
{
    (void)in_sizes; (void)n_in; (void)out_size; (void)ws_size;
    const float* bert  = (const float*)d_in[0];
    const int*   y     = (const int*)d_in[1];
    const float* Wih   = (const float*)d_in[2];
    const float* Whh   = (const float*)d_in[3];
    const float* bvec  = (const float*)d_in[4];
    const float* fcw   = (const float*)d_in[5];
    const float* fcb   = (const float*)d_in[6];
    const float* trans = (const float*)d_in[7];
    const float* stt   = (const float*)d_in[8];
    const float* ent   = (const float*)d_in[9];
    float* out = (float*)d_out;
    float* ws  = (float*)d_ws;

    unsigned short* Wihb  = (unsigned short*)(ws + OFF_WIHB);
    float* gates = ws + OFF_GATES;
    unsigned short* h1b   = (unsigned short*)(ws + OFF_H1B);
    unsigned short* bertb = (unsigned short*)(ws + OFF_BERTB);
    float* emP   = ws + OFF_EMP;
    float* em    = ws + OFF_EM;
    float* hbuf  = ws + OFF_HBUF;
    float* cst   = ws + OFF_CST;
    float* lossp = ws + OFF_LP;
    int*   stamps = (int*)(ws + OFF_STAMP);

    init_bar<<<dim3((STAMP_TOTAL + 255) / 256), dim3(256), 0, stream>>>(stamps);
    to_bf16<<<dim3(2048), dim3(256), 0, stream>>>(Wih, Wihb, 4 * G4n * Dn);
    to_bf16<<<dim3(2048), dim3(256), 0, stream>>>(bert, bertb, Bn * Sn * Dn);

    for (int l = 0; l < 2; ++l) {
        const unsigned short* A = (l == 0) ? bertb : h1b;
        for (int c = 0; c < NCH; ++c) {
            gemm_gates<<<dim3(12, 128), dim3(256), 0, stream>>>(A, Wihb, bvec, gates, l, c);
            lstm_persist<<<dim3(512), dim3(256), 0, stream>>>(gates, Whh, fcw, h1b, emP,
                                                              hbuf, cst, stamps, l, c);
        }
    }

    em_combine<<<dim3((Bn * Sn * Tn + 255) / 256), dim3(256), 0, stream>>>(emP, fcb, em);
    crf_loss<<<dim3(Bn), dim3(64), 0, stream>>>(em, y, trans, stt, ent, lossp);
    loss_final<<<dim3(1), dim3(64), 0, stream>>>(lossp, out);
    viterbi_k<<<dim3(Bn), dim3(64), 0, stream>>>(em, trans, stt, ent, out);
}